// Round 5
// baseline (262.649 us; speedup 1.0000x reference)
//
#include <hip/hip_runtime.h>
#include <math.h>

// SSD decode + per-class greedy NMS + per-image top-k for MI355X (gfx950).
//
// Exactness strategy (bit-exact vs the fp32 reference, absmax 0.0 r1-r4):
//  - fp contract OFF; every fp32 op individually rounded, same expression
//    tree as the reference
//  - exp via double (correctly-rounded fp32 exp)
//  - IoU compare: reference computes q = RN(inter/den), q > 0.45f. We use
//    (double)inter > THR*(double)den with THR = (double)0.45f + 2^-26 (the
//    rounding midpoint above 0.45f). inter/den are exact f32; THR*den fits
//    50 mantissa bits -> exact; midpoint ties round to even = 0.45f so both
//    forms say false. Bit-equivalent.
//  - tie-breaks via packed u64 key (score desc, index asc).
//
// Pipeline (3 kernels):
//  1. decode: 256 anchors/block, every thread decodes one anchor; LDS tile
//     transpose for coalesced scores_t writes.
//  2. nms_fused: per (b,c) block: histogram + scatter into 2048 score
//     buckets (counting sort), then wave-0 greedy scan that consumes whole
//     buckets <=64 at a time and sorts each chunk in-wave with a u64
//     bitonic (exact order; no full phase-C sort, no sidx round-trip).
//     Slow path (any bucket > 64: never for this data) = full insertion
//     sort + plain 64-chunks, identical to the r3 absmax-0.0 kernel.
//  3. topk: per-image bitonic top-200.

#pragma clang fp contract(off)

#define NANCH 8732
#define NB 64
#define NCLS 20            // foreground classes (class ids 1..20)
#define NMSMAX 100
#define TOPK 200
#define PRED_STRIDE 33     // 21 conf + 4 loc + 4 anchor + 4 var
#define NTHR 512
#define NE 18              // ceil(8732/512)
#define NBUCK 2048
#define DTILE 256

__device__ __forceinline__ unsigned flipf(float f) {
  unsigned u = __float_as_uint(f);
  return u ^ ((u >> 31) ? 0xFFFFFFFFu : 0x80000000u);
}

__device__ __forceinline__ float unflipf(unsigned se) {
  unsigned sbits = (se & 0x80000000u) ? (se ^ 0x80000000u) : ~se;
  return __uint_as_float(sbits);
}

// Monotone map score -> processing bucket (0 = highest). Any monotone map is
// correct (chunk sort fixes exact order); near-uniform for U(0.5,1).
__device__ __forceinline__ int bucket_of(float s) {
  float t = (s - 0.5f) * 4096.0f;
  int b = (int)t;
  b = b < 0 ? 0 : (b > (NBUCK - 1) ? (NBUCK - 1) : b);
  return (NBUCK - 1) - b;
}

// exact IoU>0.45f predicate (see header comment)
__device__ __forceinline__ bool iou_gt(float inter, float den) {
  const double THR = (double)0.45f + 0x1.0p-26;
  return (double)inter > THR * (double)den;
}

__device__ __forceinline__ float rdlanef(float v, int l) {
  return __uint_as_float(__builtin_amdgcn_readlane(__float_as_uint(v), l));
}

// ---------------------------------------------------------------- decode ---
// 256 threads = 256 anchors per block; coalesced read of the 256x33 pred
// rows into LDS; every thread decodes one anchor; transposed score writes.
__global__ __launch_bounds__(256) void decode_kernel(
    const float* __restrict__ pred,
    float* __restrict__ boxes,
    float* __restrict__ scores_t) {
#pragma clang fp contract(off)
  const int b = blockIdx.y;
  const int n0 = blockIdx.x * DTILE;
  const int na = (NANCH - n0) < DTILE ? (NANCH - n0) : DTILE;
  const int tid = threadIdx.x;

  __shared__ float lds[DTILE * PRED_STRIDE];   // 33,792 B

  const float* src = pred + ((long long)b * NANCH + n0) * PRED_STRIDE;
  const int tot = na * PRED_STRIDE;
  for (int e = tid; e < tot; e += 256) lds[e] = src[e];
  __syncthreads();

  if (tid < na) {
    const float* row = lds + tid * PRED_STRIDE;
    float l0 = row[21], l1 = row[22], l2 = row[23], l3 = row[24];
    float ax = row[25], ay = row[26], aw = row[27], ah = row[28];
    float v0 = row[29], v1 = row[30], v2 = row[31], v3 = row[32];

    float cx = (l0 * v0) * aw + ax;
    float cy = (l1 * v1) * ah + ay;
    float e2 = (float)exp((double)(l2 * v2));
    float e3 = (float)exp((double)(l3 * v3));
    float w = e2 * aw;
    float h = e3 * ah;
    float hw = 0.5f * w, hh = 0.5f * h;
    float xmin = (cx - hw) * 300.0f;
    float ymin = (cy - hh) * 300.0f;
    float xmax = (cx + hw) * 300.0f;
    float ymax = (cy + hh) * 300.0f;
    *(float4*)(boxes + ((long long)b * NANCH + n0 + tid) * 4) =
        make_float4(xmin, ymin, xmax, ymax);
  }

  if (scores_t && tid < na) {
#pragma unroll
    for (int c = 0; c < NCLS; ++c) {
      scores_t[((long long)b * NCLS + c) * NANCH + n0 + tid] =
          lds[tid * PRED_STRIDE + 1 + c];
    }
  }
}

// --------------------------------------------------------------- fused NMS ---
__global__ __launch_bounds__(NTHR) void nms_fused_kernel(
    const float* __restrict__ boxes,
    const float* __restrict__ scores_t,   // may be null -> strided fallback
    const float* __restrict__ pred,
    float* __restrict__ rows) {
#pragma clang fp contract(off)
  const int g = blockIdx.x;
  const int b = g / NCLS;
  const int c1 = g % NCLS;                // class = c1 + 1
  const int tid = threadIdx.x;
  const int lane = tid & 63;
  const int wid = tid >> 6;

  __shared__ unsigned long long keys[NANCH];     // 69,856 B
  __shared__ unsigned off[NBUCK];                //  8,192 B
  __shared__ unsigned wsum[8];
  __shared__ float4 accb[NMSMAX];                //  1,600 B
  __shared__ float acca[NMSMAX];                 //    400 B
  __shared__ int nacc_s;
  __shared__ int maxb_s;

  const float* bimg = boxes + (long long)b * NANCH * 4;
  float* grow = rows + (long long)g * NMSMAX * 6;

  // ---- phase A: histogram of candidate buckets -------------------------
  for (int q = 0; q < NBUCK / NTHR; ++q) off[tid + q * NTHR] = 0u;
  if (tid == 0) maxb_s = 0;
  __syncthreads();

  unsigned sflip[NE];
  short bkt[NE];
#pragma unroll
  for (int k = 0; k < NE; ++k) {
    int i = tid + (k << 9);
    bkt[k] = -1;
    if (i < NANCH) {
      float s = scores_t
          ? scores_t[((long long)b * NCLS + c1) * NANCH + i]
          : pred[((long long)b * NANCH + i) * PRED_STRIDE + 1 + c1];
      if (s > 0.5f) {
        int bb = bucket_of(s);
        bkt[k] = (short)bb;
        sflip[k] = flipf(s);
        atomicAdd(&off[bb], 1u);
      }
    }
  }
  __syncthreads();

  // ---- block exclusive scan over the 2048 counts (+ max bucket size) ---
  {
    unsigned v0 = off[(tid << 2) + 0], v1 = off[(tid << 2) + 1];
    unsigned v2 = off[(tid << 2) + 2], v3 = off[(tid << 2) + 3];
    unsigned mv = v0 > v1 ? v0 : v1;
    unsigned mv2 = v2 > v3 ? v2 : v3;
    mv = mv > mv2 ? mv : mv2;
    if (mv > 64u) atomicMax(&maxb_s, (int)mv);
    unsigned ls = v0 + v1 + v2 + v3;
    unsigned x = ls;
#pragma unroll
    for (int d = 1; d < 64; d <<= 1) {
      unsigned y = __shfl_up(x, d);
      if (lane >= d) x += y;
    }
    if (lane == 63) wsum[wid] = x;
    __syncthreads();
    unsigned wbase = 0;
    for (int w = 0; w < wid; ++w) wbase += wsum[w];
    unsigned base = wbase + x - ls;
    off[(tid << 2) + 0] = base;
    off[(tid << 2) + 1] = base + v0;
    off[(tid << 2) + 2] = base + v0 + v1;
    off[(tid << 2) + 3] = base + v0 + v1 + v2;
  }
  __syncthreads();

  // ---- phase B: scatter packed keys into bucket-ordered array ----------
#pragma unroll
  for (int k = 0; k < NE; ++k) {
    if (bkt[k] >= 0) {
      int i = tid + (k << 9);
      unsigned long long key = ((unsigned long long)sflip[k] << 32) |
                               (unsigned)(0xFFFFFFFFu - (unsigned)i);
      unsigned slot = atomicAdd(&off[(int)bkt[k]], 1u);
      keys[slot] = key;
    }
  }
  __syncthreads();   // off[] now holds END offsets; end[b] == start[b+1]

  const int ncand = (int)off[NBUCK - 1];
  const bool fastp = (maxb_s == 0);   // no bucket exceeds 64

  if (!fastp) {
    // ---- slow path phase C: full within-bucket insertion sort ----------
    for (int q = 0; q < NBUCK / NTHR; ++q) {
      int bk = tid * (NBUCK / NTHR) + q;
      int st = bk ? (int)off[bk - 1] : 0;
      int en = (int)off[bk];
      for (int i = st + 1; i < en; ++i) {
        unsigned long long k = keys[i];
        int j = i - 1;
        while (j >= st && keys[j] < k) { keys[j + 1] = keys[j]; --j; }
        keys[j + 1] = k;
      }
    }
    __syncthreads();
  }

  // ---- greedy scan by wave 0 -------------------------------------------
  if (wid == 0) {
    const float fcls = (float)(c1 + 1);
    int nacc = 0;

    if (ncand > 0 && fastp) {
      // ===== fast path: bucket-aligned chunks + in-wave bitonic sort ====
      int s0 = 0, bcur = 0;
      while (s0 < ncand && nacc < NMSMAX) {
        // find largest bend with off[bend-1] - s0 <= 64 (whole buckets)
        int bend = bcur;
        while (true) {
          int bi = bend + lane;
          bool ok = false;
          if (bi < NBUCK) ok = (off[bi] - (unsigned)s0) <= 64u;
          unsigned long long bal = __ballot(ok);
          int cnt = __popcll(bal);          // ok is a prefix (off monotone)
          if (cnt == 64 && bend + 64 < NBUCK) { bend += 64; continue; }
          bend += cnt;
          break;
        }
        int send = (int)off[bend - 1];
        int csz = send - s0;
        bcur = bend;
        if (csz == 0) { s0 = send; continue; }

        // load chunk keys; pad with 0 (sorts last: valid keys have hi bit)
        unsigned long long v = (lane < csz) ? keys[s0 + lane] : 0ull;
        // bitonic sort, descending by full u64 key (exact global order:
        // all keys in this chunk >= every key in later buckets)
#pragma unroll
        for (int k = 2; k <= 64; k <<= 1) {
#pragma unroll
          for (int j = k >> 1; j >= 1; j >>= 1) {
            unsigned long long o = __shfl_xor(v, j);
            bool keep_max = (((lane & k) == 0) == ((lane & j) == 0));
            v = keep_max ? (v >= o ? v : o) : (v >= o ? o : v);
          }
        }

        // gather candidate box
        float4 cb = make_float4(0.f, 0.f, 0.f, 0.f);
        if (lane < csz) {
          unsigned bidx = 0xFFFFFFFFu - (unsigned)(v & 0xFFFFFFFFu);
          cb = *(const float4*)(bimg + (long long)bidx * 4);
        }
        const float ca = fmaxf(cb.z - cb.x, 0.f) * fmaxf(cb.w - cb.y, 0.f);
        bool su = lane >= csz;

        // pre-test vs all accepts made before this chunk
        for (int j = 0; j < nacc; ++j) {
          float4 ab = accb[j];                // uniform addr -> broadcast
          float aa = acca[j];
          float ix0 = fmaxf(ab.x, cb.x), iy0 = fmaxf(ab.y, cb.y);
          float ix1 = fminf(ab.z, cb.z), iy1 = fminf(ab.w, cb.w);
          float inter = fmaxf(ix1 - ix0, 0.f) * fmaxf(iy1 - iy0, 0.f);
          float den = fmaxf((aa + ca) - inter, 1e-8f);
          su = su || iou_gt(inter, den);
        }

        // serial resolve: accept lowest live lane, suppress vs it, repeat
        unsigned long long live = __ballot(!su);
        while (live && nacc < NMSMAX) {
          int l = __ffsll(live) - 1;
          float bx = rdlanef(cb.x, l), by = rdlanef(cb.y, l);
          float bz = rdlanef(cb.z, l), bw = rdlanef(cb.w, l);
          unsigned khi = __builtin_amdgcn_readlane((unsigned)(v >> 32), l);
          float aa = fmaxf(bz - bx, 0.f) * fmaxf(bw - by, 0.f);
          if (lane == 0) {
            float* gr = grow + nacc * 6;
            gr[0] = fcls;
            gr[1] = unflipf(khi);
            gr[2] = bx; gr[3] = by; gr[4] = bz; gr[5] = bw;
            accb[nacc] = make_float4(bx, by, bz, bw);
            acca[nacc] = aa;
          }
          ++nacc;
          float ix0 = fmaxf(bx, cb.x), iy0 = fmaxf(by, cb.y);
          float ix1 = fminf(bz, cb.z), iy1 = fminf(bw, cb.w);
          float inter = fmaxf(ix1 - ix0, 0.f) * fmaxf(iy1 - iy0, 0.f);
          float den = fmaxf((aa + ca) - inter, 1e-8f);
          su = su || iou_gt(inter, den) || (lane == l);
          live = __ballot(!su);
        }

        s0 = send;
      }
    } else if (ncand > 0) {
      // ===== slow path: plain 64-chunks over fully sorted keys ==========
      const int nchunk = (ncand + 63) >> 6;
      int slot0 = lane < ncand ? lane : 0;
      unsigned long long kcur = keys[slot0];
      float4 cbv;
      {
        unsigned bidx = 0xFFFFFFFFu - (unsigned)(kcur & 0xFFFFFFFFu);
        cbv = *(const float4*)(bimg + (long long)bidx * 4);
      }

      for (int c = 0; c < nchunk && nacc < NMSMAX; ++c) {
        unsigned long long knxt = 0ull;
        float4 cbn = make_float4(0.f, 0.f, 0.f, 0.f);
        if (c + 1 < nchunk) {
          int sl = ((c + 1) << 6) + lane;
          int cl = sl < ncand ? sl : 0;
          knxt = keys[cl];
          unsigned bidx = 0xFFFFFFFFu - (unsigned)(knxt & 0xFFFFFFFFu);
          cbn = *(const float4*)(bimg + (long long)bidx * 4);
        }

        const float4 cb = cbv;
        const float ca = fmaxf(cb.z - cb.x, 0.f) * fmaxf(cb.w - cb.y, 0.f);
        bool su = ((c << 6) + lane) >= ncand;

        for (int j = 0; j < nacc; ++j) {
          float4 ab = accb[j];
          float aa = acca[j];
          float ix0 = fmaxf(ab.x, cb.x), iy0 = fmaxf(ab.y, cb.y);
          float ix1 = fminf(ab.z, cb.z), iy1 = fminf(ab.w, cb.w);
          float inter = fmaxf(ix1 - ix0, 0.f) * fmaxf(iy1 - iy0, 0.f);
          float den = fmaxf((aa + ca) - inter, 1e-8f);
          su = su || iou_gt(inter, den);
        }

        unsigned long long live = __ballot(!su);
        while (live && nacc < NMSMAX) {
          int l = __ffsll(live) - 1;
          float bx = rdlanef(cb.x, l), by = rdlanef(cb.y, l);
          float bz = rdlanef(cb.z, l), bw = rdlanef(cb.w, l);
          unsigned khi = __builtin_amdgcn_readlane((unsigned)(kcur >> 32), l);
          float aa = fmaxf(bz - bx, 0.f) * fmaxf(bw - by, 0.f);
          if (lane == 0) {
            float* gr = grow + nacc * 6;
            gr[0] = fcls;
            gr[1] = unflipf(khi);
            gr[2] = bx; gr[3] = by; gr[4] = bz; gr[5] = bw;
            accb[nacc] = make_float4(bx, by, bz, bw);
            acca[nacc] = aa;
          }
          ++nacc;
          float ix0 = fmaxf(bx, cb.x), iy0 = fmaxf(by, cb.y);
          float ix1 = fminf(bz, cb.z), iy1 = fminf(bw, cb.w);
          float inter = fmaxf(ix1 - ix0, 0.f) * fmaxf(iy1 - iy0, 0.f);
          float den = fmaxf((aa + ca) - inter, 1e-8f);
          su = su || iou_gt(inter, den) || (lane == l);
          live = __ballot(!su);
        }

        kcur = knxt; cbv = cbn;
      }
    }

    if (lane == 0) nacc_s = nacc;
  }
  __syncthreads();

  // ---- zero-fill rows past the accepted count (ref: ok = 0 rows) -------
  for (int j = nacc_s * 6 + tid; j < NMSMAX * 6; j += NTHR) grow[j] = 0.f;
}

// ----------------------------------------------------------------- top-k ---
__global__ __launch_bounds__(512) void topk_kernel(const float* __restrict__ rows,
                                                   float* __restrict__ out) {
  __shared__ unsigned long long key[2048];
  const int b = blockIdx.x;
  const int tid = threadIdx.x;  // 512 threads
  const float* rb = rows + (long long)b * (NCLS * NMSMAX) * 6;

  for (int e = tid; e < 2048; e += 512) {
    unsigned long long k = 0ull;  // padding sorts last (scores are >= 0)
    if (e < NCLS * NMSMAX) {
      float s = rb[e * 6 + 1];
      unsigned se = flipf(s);
      k = ((unsigned long long)se << 32) | (unsigned)(0xFFFFFFFFu - (unsigned)e);
    }
    key[e] = k;
  }
  __syncthreads();

  for (unsigned k2 = 2; k2 <= 2048; k2 <<= 1) {
    for (unsigned j = k2 >> 1; j > 0; j >>= 1) {
      for (unsigned t = tid; t < 1024; t += 512) {
        unsigned i = t + (t & ~(j - 1));
        unsigned l = i + j;
        bool up = ((i & k2) == 0);
        unsigned long long a = key[i], c = key[l];
        if (up ? (a < c) : (a > c)) { key[i] = c; key[l] = a; }
      }
      __syncthreads();
    }
  }

  if (tid < TOPK) {
    unsigned long long kk = key[tid];
    unsigned e = 0xFFFFFFFFu - (unsigned)(kk & 0xFFFFFFFFu);
    const float* src = rb + (long long)e * 6;
    float* dst = out + ((long long)b * TOPK + tid) * 6;
#pragma unroll
    for (int j = 0; j < 6; ++j) dst[j] = src[j];
  }
}

// ---------------------------------------------------------------- launch ---
extern "C" void kernel_launch(void* const* d_in, const int* in_sizes, int n_in,
                              void* d_out, int out_size, void* d_ws, size_t ws_size,
                              hipStream_t stream) {
  const float* pred = (const float*)d_in[0];
  float* out = (float*)d_out;
  float* ws = (float*)d_ws;

  const long long boxes_f = (long long)NB * NANCH * 4;           //  2,235,392
  const long long rows_f  = (long long)NB * NCLS * NMSMAX * 6;   //    768,000
  const long long st_f    = (long long)NB * NCLS * NANCH;        // 11,176,960

  float* boxes = ws;
  float* rows  = ws + boxes_f;
  float* st    = ws + boxes_f + rows_f;
  size_t need_scores = (size_t)(boxes_f + rows_f + st_f) * sizeof(float);
  float* scores_t = (ws_size >= need_scores) ? st : nullptr;

  dim3 dgrid((NANCH + DTILE - 1) / DTILE, NB);
  decode_kernel<<<dgrid, 256, 0, stream>>>(pred, boxes, scores_t);
  nms_fused_kernel<<<NB * NCLS, NTHR, 0, stream>>>(boxes, scores_t, pred, rows);
  topk_kernel<<<NB, 512, 0, stream>>>(rows, out);
}

// Round 9
// 259.662 us; speedup vs baseline: 1.0115x; 1.0115x over previous
//
#include <hip/hip_runtime.h>
#include <math.h>

// SSD decode + per-class greedy NMS + per-image top-k for MI355X (gfx950).
//
// Exactness strategy (bit-exact vs the fp32 reference, absmax 0.0 r1-r5):
//  - fp contract OFF; every fp32 op individually rounded, same expression
//    tree as the reference
//  - exp via double (correctly-rounded fp32 exp)
//  - IoU compare: reference computes q = RN(inter/den), q > 0.45f. We use
//    (double)inter > THR*(double)den with THR = (double)0.45f + 2^-26 (the
//    rounding midpoint above 0.45f). inter/den are exact f32; THR*den fits
//    50 mantissa bits -> exact; midpoint ties round to even = 0.45f so both
//    forms say false. Bit-equivalent.
//  - tie-breaks via packed u64 key (score desc, index asc).
//
// r8 bug fixed here: phase A/B covered only 8704 of 8732 anchors (missing
// 28). NANCH = 4*2183 exactly, so we run 5 predicated float4 passes.
//
// Pipeline (4 kernels):
//  1. decode: 256 anchors/block; LDS tile transpose -> coalesced scores_t.
//  2. sort: per (b,c) 512-thread block. u16-only LDS (~26.5 KB -> 4 blk/CU):
//     histogram into 2048 score buckets + prefix scan + u16 index scatter;
//     then ALL 8 waves sort bucket-aligned <=64 chunks with an in-wave u64
//     bitonic (keys rebuilt from gathered L2-hot scores) and write fully-
//     sorted u16 indices to global. Slow path (bucket>64: never here) =
//     exact insertion sort with gathered-score compares.
//  3. scan: one 64-thread block per (b,c); chunked greedy accept (r4 code).
//  4. topk: per-image bitonic top-200.

#pragma clang fp contract(off)

#define NANCH 8732
#define NF4 2183           // NANCH / 4, exact
#define NB 64
#define NCLS 20            // foreground classes (class ids 1..20)
#define NMSMAX 100
#define TOPK 200
#define PRED_STRIDE 33     // 21 conf + 4 loc + 4 anchor + 4 var
#define NTHR 512
#define NE 18              // ceil(8732/512)
#define NBUCK 2048
#define DTILE 256

__device__ __forceinline__ unsigned flipf(float f) {
  unsigned u = __float_as_uint(f);
  return u ^ ((u >> 31) ? 0xFFFFFFFFu : 0x80000000u);
}

__device__ __forceinline__ float unflipf(unsigned se) {
  unsigned sbits = (se & 0x80000000u) ? (se ^ 0x80000000u) : ~se;
  return __uint_as_float(sbits);
}

// Monotone map score -> processing bucket (0 = highest). Any monotone map is
// correct (chunk sort fixes exact order); near-uniform for U(0.5,1).
__device__ __forceinline__ int bucket_of(float s) {
  float t = (s - 0.5f) * 4096.0f;
  int b = (int)t;
  b = b < 0 ? 0 : (b > (NBUCK - 1) ? (NBUCK - 1) : b);
  return (NBUCK - 1) - b;
}

// exact IoU>0.45f predicate (see header comment)
__device__ __forceinline__ bool iou_gt(float inter, float den) {
  const double THR = (double)0.45f + 0x1.0p-26;
  return (double)inter > THR * (double)den;
}

__device__ __forceinline__ float rdlanef(float v, int l) {
  return __uint_as_float(__builtin_amdgcn_readlane(__float_as_uint(v), l));
}

// ---------------------------------------------------------------- decode ---
// 256 threads = 256 anchors per block; coalesced read of the 256x33 pred
// rows into LDS; every thread decodes one anchor; transposed score writes.
__global__ __launch_bounds__(256) void decode_kernel(
    const float* __restrict__ pred,
    float* __restrict__ boxes,
    float* __restrict__ scores_t) {
#pragma clang fp contract(off)
  const int b = blockIdx.y;
  const int n0 = blockIdx.x * DTILE;
  const int na = (NANCH - n0) < DTILE ? (NANCH - n0) : DTILE;
  const int tid = threadIdx.x;

  __shared__ float lds[DTILE * PRED_STRIDE];   // 33,792 B

  const float* src = pred + ((long long)b * NANCH + n0) * PRED_STRIDE;
  const int tot = na * PRED_STRIDE;
  for (int e = tid; e < tot; e += 256) lds[e] = src[e];
  __syncthreads();

  if (tid < na) {
    const float* row = lds + tid * PRED_STRIDE;
    float l0 = row[21], l1 = row[22], l2 = row[23], l3 = row[24];
    float ax = row[25], ay = row[26], aw = row[27], ah = row[28];
    float v0 = row[29], v1 = row[30], v2 = row[31], v3 = row[32];

    float cx = (l0 * v0) * aw + ax;
    float cy = (l1 * v1) * ah + ay;
    float e2 = (float)exp((double)(l2 * v2));
    float e3 = (float)exp((double)(l3 * v3));
    float w = e2 * aw;
    float h = e3 * ah;
    float hw = 0.5f * w, hh = 0.5f * h;
    float xmin = (cx - hw) * 300.0f;
    float ymin = (cy - hh) * 300.0f;
    float xmax = (cx + hw) * 300.0f;
    float ymax = (cy + hh) * 300.0f;
    *(float4*)(boxes + ((long long)b * NANCH + n0 + tid) * 4) =
        make_float4(xmin, ymin, xmax, ymax);

    if (scores_t) {
#pragma unroll
      for (int c = 0; c < NCLS; ++c) {
        scores_t[((long long)b * NCLS + c) * NANCH + n0 + tid] =
            lds[tid * PRED_STRIDE + 1 + c];
      }
    }
  }
}

// -------------------------------------------------------------------- sort ---
__global__ __launch_bounds__(NTHR) void sort_kernel(
    const float* __restrict__ scores_t,
    unsigned short* __restrict__ sidx,
    int* __restrict__ ncand_g) {
#pragma clang fp contract(off)
  const int g = blockIdx.x;
  const int b = g / NCLS;
  const int c1 = g % NCLS;
  const int tid = threadIdx.x;
  const int lane = tid & 63;
  const int wid = tid >> 6;

  __shared__ unsigned short sidx_s[NANCH];   // 17,464 B
  __shared__ unsigned off[NBUCK];            //  8,192 B
  __shared__ unsigned wsum[8];
  __shared__ int maxb_s;

  const float* srow = scores_t + ((long long)b * NCLS + c1) * NANCH;

  // ---- phase A: histogram of candidate buckets (float4 loads) ----------
  // 5 predicated passes cover all NF4=2183 float4s (= all 8732 anchors).
  for (int q = 0; q < NBUCK / NTHR; ++q) off[tid + q * NTHR] = 0u;
  if (tid == 0) maxb_s = 0;
  __syncthreads();

  short bkt[20];
#pragma unroll
  for (int it = 0; it < 5; ++it) {
    int f4 = tid + it * NTHR;
    bool valid = f4 < NF4;
    float4 sv = valid ? ((const float4*)srow)[f4]
                      : make_float4(0.f, 0.f, 0.f, 0.f);
    float ss[4] = {sv.x, sv.y, sv.z, sv.w};
#pragma unroll
    for (int c = 0; c < 4; ++c) {
      short bb = -1;
      if (valid && ss[c] > 0.5f) {
        bb = (short)bucket_of(ss[c]);
        atomicAdd(&off[(int)bb], 1u);
      }
      bkt[it * 4 + c] = bb;
    }
  }
  __syncthreads();

  // ---- block exclusive scan over the 2048 counts (+ max bucket size) ---
  {
    unsigned v0 = off[(tid << 2) + 0], v1 = off[(tid << 2) + 1];
    unsigned v2 = off[(tid << 2) + 2], v3 = off[(tid << 2) + 3];
    unsigned mv = v0 > v1 ? v0 : v1;
    unsigned mv2 = v2 > v3 ? v2 : v3;
    mv = mv > mv2 ? mv : mv2;
    if (mv > 64u) atomicMax(&maxb_s, (int)mv);
    unsigned ls = v0 + v1 + v2 + v3;
    unsigned x = ls;
#pragma unroll
    for (int d = 1; d < 64; d <<= 1) {
      unsigned y = __shfl_up(x, d);
      if (lane >= d) x += y;
    }
    if (lane == 63) wsum[wid] = x;
    __syncthreads();
    unsigned wbase = 0;
    for (int w = 0; w < wid; ++w) wbase += wsum[w];
    unsigned base = wbase + x - ls;
    off[(tid << 2) + 0] = base;
    off[(tid << 2) + 1] = base + v0;
    off[(tid << 2) + 2] = base + v0 + v1;
    off[(tid << 2) + 3] = base + v0 + v1 + v2;
  }
  __syncthreads();

  // ---- phase B: scatter u16 indices into bucket-ordered array ----------
#pragma unroll
  for (int it = 0; it < 5; ++it) {
#pragma unroll
    for (int c = 0; c < 4; ++c) {
      short bb = bkt[it * 4 + c];
      if (bb >= 0) {
        int i = (tid + it * NTHR) * 4 + c;
        unsigned slot = atomicAdd(&off[(int)bb], 1u);
        sidx_s[slot] = (unsigned short)i;
      }
    }
  }
  __syncthreads();   // off[] now holds END offsets; end[b] == start[b+1]

  const int ncand = (int)off[NBUCK - 1];
  unsigned short* sg = sidx + (long long)g * NANCH;

  if (maxb_s == 0) {
    // ===== fast path: all 8 waves sort bucket-aligned chunks ============
    // Each wave redundantly walks the bucket offsets (uniform LDS data)
    // and owns chunks with ordinal == wid (mod 8). Chunk = maximal run of
    // whole buckets totaling <=64 candidates; all chunk keys >= all later
    // keys, so per-chunk bitonic sort on the full u64 key (score desc,
    // index asc) yields exact global order.
    int s0 = 0, bcur = 0, cidx = 0;
    while (s0 < ncand) {
      int bend = bcur;
      while (true) {
        int bi = bend + lane;
        bool ok = (bi < NBUCK) && ((off[bi] - (unsigned)s0) <= 64u);
        unsigned long long bal = __ballot(ok);
        int cnt = __popcll(bal);            // ok is a prefix (off monotone)
        if (cnt == 64 && bend + 64 < NBUCK) { bend += 64; continue; }
        bend += cnt;
        break;
      }
      int send = (int)off[bend - 1];
      int csz = send - s0;
      bcur = bend;
      if (csz > 0) {
        if ((cidx & 7) == wid) {
          unsigned long long v = 0ull;      // padding sorts last
          if (lane < csz) {
            unsigned id = sidx_s[s0 + lane];
            float s = srow[id];             // L2-hot gather
            v = ((unsigned long long)flipf(s) << 32) |
                (unsigned)(0xFFFFFFFFu - id);
          }
          // bitonic sort, descending by full u64 key
#pragma unroll
          for (int k = 2; k <= 64; k <<= 1) {
#pragma unroll
            for (int j = k >> 1; j >= 1; j >>= 1) {
              unsigned long long o = __shfl_xor(v, j);
              bool keep_max = (((lane & k) == 0) == ((lane & j) == 0));
              v = keep_max ? (v >= o ? v : o) : (v >= o ? o : v);
            }
          }
          if (lane < csz) {
            sg[s0 + lane] =
                (unsigned short)(0xFFFFFFFFu - (unsigned)(v & 0xFFFFFFFFu));
          }
        }
        ++cidx;
      }
      s0 = send;
    }
  } else {
    // ===== slow path: exact per-bucket insertion sort ===================
    // Order: score desc, index asc (== u64 key desc). Correctness-only
    // path; never taken for this data distribution.
    for (int q = 0; q < NBUCK / NTHR; ++q) {
      int bk = tid * (NBUCK / NTHR) + q;
      int st = bk ? (int)off[bk - 1] : 0;
      int en = (int)off[bk];
      for (int i = st + 1; i < en; ++i) {
        unsigned short id = sidx_s[i];
        float s = srow[id];
        int j = i - 1;
        while (j >= st) {
          unsigned short jd = sidx_s[j];
          float js = srow[jd];
          bool jless = (js < s) || (js == s && jd > id);  // key[j] < key[i]
          if (!jless) break;
          sidx_s[j + 1] = jd;
          --j;
        }
        sidx_s[j + 1] = id;
      }
    }
    __syncthreads();
    for (int s = tid; s < ncand; s += NTHR) sg[s] = sidx_s[s];
  }

  if (tid == 0) ncand_g[g] = ncand;
}

// -------------------------------------------------------------------- scan ---
// One wave per (b,c): chunked greedy accept over fully-sorted candidates.
// Logic byte-identical to the r4 absmax-0.0 scan kernel.
__global__ __launch_bounds__(64) void scan_kernel(
    const float* __restrict__ boxes,
    const float* __restrict__ scores_t,
    const unsigned short* __restrict__ sidx,
    const int* __restrict__ ncand_g,
    float* __restrict__ rows) {
#pragma clang fp contract(off)
  const int g = blockIdx.x;
  const int b = g / NCLS;
  const int c1 = g % NCLS;
  const int lane = threadIdx.x;

  __shared__ float4 accb[NMSMAX];    // 1600 B
  __shared__ float acca[NMSMAX];     //  400 B

  const float* bimg = boxes + (long long)b * NANCH * 4;
  const float* srow = scores_t + ((long long)b * NCLS + c1) * NANCH;
  const unsigned short* sg = sidx + (long long)g * NANCH;
  float* grow = rows + (long long)g * NMSMAX * 6;

  const int ncand = ncand_g[g];
  int nacc = 0;

  if (ncand > 0) {
    const float fcls = (float)(c1 + 1);
    const int nchunk = (ncand + 63) >> 6;

    // prefetch chunk 0
    int cl0 = lane < ncand ? lane : ncand - 1;
    unsigned id0 = sg[cl0];
    float4 cbv = *(const float4*)(bimg + (long long)id0 * 4);
    float scv = srow[id0];

    for (int c = 0; c < nchunk && nacc < NMSMAX; ++c) {
      // prefetch next chunk, hidden under compute
      float4 cbn = make_float4(0.f, 0.f, 0.f, 0.f);
      float scn = 0.f;
      if (c + 1 < nchunk) {
        int sl = ((c + 1) << 6) + lane;
        int cl = sl < ncand ? sl : ncand - 1;
        unsigned id = sg[cl];
        cbn = *(const float4*)(bimg + (long long)id * 4);
        scn = srow[id];
      }

      const float4 cb = cbv;
      const float sc = scv;
      const float ca = fmaxf(cb.z - cb.x, 0.f) * fmaxf(cb.w - cb.y, 0.f);
      bool su = ((c << 6) + lane) >= ncand;   // invalid lanes start dead

      // pre-test vs all accepts made before this chunk
      for (int j = 0; j < nacc; ++j) {
        float4 ab = accb[j];                  // uniform addr -> broadcast
        float aa = acca[j];
        float ix0 = fmaxf(ab.x, cb.x), iy0 = fmaxf(ab.y, cb.y);
        float ix1 = fminf(ab.z, cb.z), iy1 = fminf(ab.w, cb.w);
        float inter = fmaxf(ix1 - ix0, 0.f) * fmaxf(iy1 - iy0, 0.f);
        float den = fmaxf((aa + ca) - inter, 1e-8f);
        su = su || iou_gt(inter, den);
      }

      // serial resolve: accept lowest live lane, suppress vs it, repeat
      unsigned long long live = __ballot(!su);
      while (live && nacc < NMSMAX) {
        int l = __ffsll(live) - 1;
        float bx = rdlanef(cb.x, l), by = rdlanef(cb.y, l);
        float bz = rdlanef(cb.z, l), bw = rdlanef(cb.w, l);
        float bs = rdlanef(sc, l);
        float aa = fmaxf(bz - bx, 0.f) * fmaxf(bw - by, 0.f);
        if (lane == 0) {
          float* gr = grow + nacc * 6;
          gr[0] = fcls;
          gr[1] = bs;
          gr[2] = bx; gr[3] = by; gr[4] = bz; gr[5] = bw;
          accb[nacc] = make_float4(bx, by, bz, bw);
          acca[nacc] = aa;
        }
        ++nacc;
        // incremental suppression vs the new accept
        float ix0 = fmaxf(bx, cb.x), iy0 = fmaxf(by, cb.y);
        float ix1 = fminf(bz, cb.z), iy1 = fminf(bw, cb.w);
        float inter = fmaxf(ix1 - ix0, 0.f) * fmaxf(iy1 - iy0, 0.f);
        float den = fmaxf((aa + ca) - inter, 1e-8f);
        su = su || iou_gt(inter, den) || (lane == l);
        live = __ballot(!su);
      }

      cbv = cbn; scv = scn;
    }
  }

  // ---- zero-fill rows past the accepted count (ref: ok = 0 rows) -------
  for (int j = nacc * 6 + lane; j < NMSMAX * 6; j += 64) grow[j] = 0.f;
}

// ----------------------------------------------------------------- top-k ---
__global__ __launch_bounds__(512) void topk_kernel(const float* __restrict__ rows,
                                                   float* __restrict__ out) {
  __shared__ unsigned long long key[2048];
  const int b = blockIdx.x;
  const int tid = threadIdx.x;  // 512 threads
  const float* rb = rows + (long long)b * (NCLS * NMSMAX) * 6;

  for (int e = tid; e < 2048; e += 512) {
    unsigned long long k = 0ull;  // padding sorts last (scores are >= 0)
    if (e < NCLS * NMSMAX) {
      float s = rb[e * 6 + 1];
      unsigned se = flipf(s);
      k = ((unsigned long long)se << 32) | (unsigned)(0xFFFFFFFFu - (unsigned)e);
    }
    key[e] = k;
  }
  __syncthreads();

  for (unsigned k2 = 2; k2 <= 2048; k2 <<= 1) {
    for (unsigned j = k2 >> 1; j > 0; j >>= 1) {
      for (unsigned t = tid; t < 1024; t += 512) {
        unsigned i = t + (t & ~(j - 1));
        unsigned l = i + j;
        bool up = ((i & k2) == 0);
        unsigned long long a = key[i], c = key[l];
        if (up ? (a < c) : (a > c)) { key[i] = c; key[l] = a; }
      }
      __syncthreads();
    }
  }

  if (tid < TOPK) {
    unsigned long long kk = key[tid];
    unsigned e = 0xFFFFFFFFu - (unsigned)(kk & 0xFFFFFFFFu);
    const float* src = rb + (long long)e * 6;
    float* dst = out + ((long long)b * TOPK + tid) * 6;
#pragma unroll
    for (int j = 0; j < 6; ++j) dst[j] = src[j];
  }
}

// ------------------------------------------------------- fused NMS fallback ---
// Round-5 kernel logic (absmax 0.0), reading scores straight from pred.
// Used only if d_ws is too small for the split pipeline.
__global__ __launch_bounds__(NTHR) void nms_fused_kernel(
    const float* __restrict__ boxes,
    const float* __restrict__ pred,
    float* __restrict__ rows) {
#pragma clang fp contract(off)
  const int g = blockIdx.x;
  const int b = g / NCLS;
  const int c1 = g % NCLS;
  const int tid = threadIdx.x;
  const int lane = tid & 63;
  const int wid = tid >> 6;

  __shared__ unsigned long long keys[NANCH];
  __shared__ unsigned off[NBUCK];
  __shared__ unsigned wsum[8];
  __shared__ float4 accb[NMSMAX];
  __shared__ float acca[NMSMAX];
  __shared__ int nacc_s;
  __shared__ int maxb_s;

  const float* bimg = boxes + (long long)b * NANCH * 4;
  float* grow = rows + (long long)g * NMSMAX * 6;

  for (int q = 0; q < NBUCK / NTHR; ++q) off[tid + q * NTHR] = 0u;
  if (tid == 0) maxb_s = 0;
  __syncthreads();

  unsigned sflip[NE];
  short bkt[NE];
#pragma unroll
  for (int k = 0; k < NE; ++k) {
    int i = tid + (k << 9);
    bkt[k] = -1;
    if (i < NANCH) {
      float s = pred[((long long)b * NANCH + i) * PRED_STRIDE + 1 + c1];
      if (s > 0.5f) {
        int bb = bucket_of(s);
        bkt[k] = (short)bb;
        sflip[k] = flipf(s);
        atomicAdd(&off[bb], 1u);
      }
    }
  }
  __syncthreads();

  {
    unsigned v0 = off[(tid << 2) + 0], v1 = off[(tid << 2) + 1];
    unsigned v2 = off[(tid << 2) + 2], v3 = off[(tid << 2) + 3];
    unsigned mv = v0 > v1 ? v0 : v1;
    unsigned mv2 = v2 > v3 ? v2 : v3;
    mv = mv > mv2 ? mv : mv2;
    if (mv > 64u) atomicMax(&maxb_s, (int)mv);
    unsigned ls = v0 + v1 + v2 + v3;
    unsigned x = ls;
#pragma unroll
    for (int d = 1; d < 64; d <<= 1) {
      unsigned y = __shfl_up(x, d);
      if (lane >= d) x += y;
    }
    if (lane == 63) wsum[wid] = x;
    __syncthreads();
    unsigned wbase = 0;
    for (int w = 0; w < wid; ++w) wbase += wsum[w];
    unsigned base = wbase + x - ls;
    off[(tid << 2) + 0] = base;
    off[(tid << 2) + 1] = base + v0;
    off[(tid << 2) + 2] = base + v0 + v1;
    off[(tid << 2) + 3] = base + v0 + v1 + v2;
  }
  __syncthreads();

#pragma unroll
  for (int k = 0; k < NE; ++k) {
    if (bkt[k] >= 0) {
      int i = tid + (k << 9);
      unsigned long long key = ((unsigned long long)sflip[k] << 32) |
                               (unsigned)(0xFFFFFFFFu - (unsigned)i);
      unsigned slot = atomicAdd(&off[(int)bkt[k]], 1u);
      keys[slot] = key;
    }
  }
  __syncthreads();

  const int ncand = (int)off[NBUCK - 1];
  const bool fastp = (maxb_s == 0);

  if (!fastp) {
    for (int q = 0; q < NBUCK / NTHR; ++q) {
      int bk = tid * (NBUCK / NTHR) + q;
      int st = bk ? (int)off[bk - 1] : 0;
      int en = (int)off[bk];
      for (int i = st + 1; i < en; ++i) {
        unsigned long long k = keys[i];
        int j = i - 1;
        while (j >= st && keys[j] < k) { keys[j + 1] = keys[j]; --j; }
        keys[j + 1] = k;
      }
    }
    __syncthreads();
  }

  if (wid == 0) {
    const float fcls = (float)(c1 + 1);
    int nacc = 0;

    if (ncand > 0 && fastp) {
      int s0 = 0, bcur = 0;
      while (s0 < ncand && nacc < NMSMAX) {
        int bend = bcur;
        while (true) {
          int bi = bend + lane;
          bool ok = false;
          if (bi < NBUCK) ok = (off[bi] - (unsigned)s0) <= 64u;
          unsigned long long bal = __ballot(ok);
          int cnt = __popcll(bal);
          if (cnt == 64 && bend + 64 < NBUCK) { bend += 64; continue; }
          bend += cnt;
          break;
        }
        int send = (int)off[bend - 1];
        int csz = send - s0;
        bcur = bend;
        if (csz == 0) { s0 = send; continue; }

        unsigned long long v = (lane < csz) ? keys[s0 + lane] : 0ull;
#pragma unroll
        for (int k = 2; k <= 64; k <<= 1) {
#pragma unroll
          for (int j = k >> 1; j >= 1; j >>= 1) {
            unsigned long long o = __shfl_xor(v, j);
            bool keep_max = (((lane & k) == 0) == ((lane & j) == 0));
            v = keep_max ? (v >= o ? v : o) : (v >= o ? o : v);
          }
        }

        float4 cb = make_float4(0.f, 0.f, 0.f, 0.f);
        if (lane < csz) {
          unsigned bidx = 0xFFFFFFFFu - (unsigned)(v & 0xFFFFFFFFu);
          cb = *(const float4*)(bimg + (long long)bidx * 4);
        }
        const float ca = fmaxf(cb.z - cb.x, 0.f) * fmaxf(cb.w - cb.y, 0.f);
        bool su = lane >= csz;

        for (int j = 0; j < nacc; ++j) {
          float4 ab = accb[j];
          float aa = acca[j];
          float ix0 = fmaxf(ab.x, cb.x), iy0 = fmaxf(ab.y, cb.y);
          float ix1 = fminf(ab.z, cb.z), iy1 = fminf(ab.w, cb.w);
          float inter = fmaxf(ix1 - ix0, 0.f) * fmaxf(iy1 - iy0, 0.f);
          float den = fmaxf((aa + ca) - inter, 1e-8f);
          su = su || iou_gt(inter, den);
        }

        unsigned long long live = __ballot(!su);
        while (live && nacc < NMSMAX) {
          int l = __ffsll(live) - 1;
          float bx = rdlanef(cb.x, l), by = rdlanef(cb.y, l);
          float bz = rdlanef(cb.z, l), bw = rdlanef(cb.w, l);
          unsigned khi = __builtin_amdgcn_readlane((unsigned)(v >> 32), l);
          float aa = fmaxf(bz - bx, 0.f) * fmaxf(bw - by, 0.f);
          if (lane == 0) {
            float* gr = grow + nacc * 6;
            gr[0] = fcls;
            gr[1] = unflipf(khi);
            gr[2] = bx; gr[3] = by; gr[4] = bz; gr[5] = bw;
            accb[nacc] = make_float4(bx, by, bz, bw);
            acca[nacc] = aa;
          }
          ++nacc;
          float ix0 = fmaxf(bx, cb.x), iy0 = fmaxf(by, cb.y);
          float ix1 = fminf(bz, cb.z), iy1 = fminf(bw, cb.w);
          float inter = fmaxf(ix1 - ix0, 0.f) * fmaxf(iy1 - iy0, 0.f);
          float den = fmaxf((aa + ca) - inter, 1e-8f);
          su = su || iou_gt(inter, den) || (lane == l);
          live = __ballot(!su);
        }

        s0 = send;
      }
    } else if (ncand > 0) {
      const int nchunk = (ncand + 63) >> 6;
      int slot0 = lane < ncand ? lane : 0;
      unsigned long long kcur = keys[slot0];
      float4 cbv;
      {
        unsigned bidx = 0xFFFFFFFFu - (unsigned)(kcur & 0xFFFFFFFFu);
        cbv = *(const float4*)(bimg + (long long)bidx * 4);
      }

      for (int c = 0; c < nchunk && nacc < NMSMAX; ++c) {
        unsigned long long knxt = 0ull;
        float4 cbn = make_float4(0.f, 0.f, 0.f, 0.f);
        if (c + 1 < nchunk) {
          int sl = ((c + 1) << 6) + lane;
          int cl = sl < ncand ? sl : 0;
          knxt = keys[cl];
          unsigned bidx = 0xFFFFFFFFu - (unsigned)(knxt & 0xFFFFFFFFu);
          cbn = *(const float4*)(bimg + (long long)bidx * 4);
        }

        const float4 cb = cbv;
        const float ca = fmaxf(cb.z - cb.x, 0.f) * fmaxf(cb.w - cb.y, 0.f);
        bool su = ((c << 6) + lane) >= ncand;

        for (int j = 0; j < nacc; ++j) {
          float4 ab = accb[j];
          float aa = acca[j];
          float ix0 = fmaxf(ab.x, cb.x), iy0 = fmaxf(ab.y, cb.y);
          float ix1 = fminf(ab.z, cb.z), iy1 = fminf(ab.w, cb.w);
          float inter = fmaxf(ix1 - ix0, 0.f) * fmaxf(iy1 - iy0, 0.f);
          float den = fmaxf((aa + ca) - inter, 1e-8f);
          su = su || iou_gt(inter, den);
        }

        unsigned long long live = __ballot(!su);
        while (live && nacc < NMSMAX) {
          int l = __ffsll(live) - 1;
          float bx = rdlanef(cb.x, l), by = rdlanef(cb.y, l);
          float bz = rdlanef(cb.z, l), bw = rdlanef(cb.w, l);
          unsigned khi = __builtin_amdgcn_readlane((unsigned)(kcur >> 32), l);
          float aa = fmaxf(bz - bx, 0.f) * fmaxf(bw - by, 0.f);
          if (lane == 0) {
            float* gr = grow + nacc * 6;
            gr[0] = fcls;
            gr[1] = unflipf(khi);
            gr[2] = bx; gr[3] = by; gr[4] = bz; gr[5] = bw;
            accb[nacc] = make_float4(bx, by, bz, bw);
            acca[nacc] = aa;
          }
          ++nacc;
          float ix0 = fmaxf(bx, cb.x), iy0 = fmaxf(by, cb.y);
          float ix1 = fminf(bz, cb.z), iy1 = fminf(bw, cb.w);
          float inter = fmaxf(ix1 - ix0, 0.f) * fmaxf(iy1 - iy0, 0.f);
          float den = fmaxf((aa + ca) - inter, 1e-8f);
          su = su || iou_gt(inter, den) || (lane == l);
          live = __ballot(!su);
        }

        kcur = knxt; cbv = cbn;
      }
    }

    if (lane == 0) nacc_s = nacc;
  }
  __syncthreads();

  for (int j = nacc_s * 6 + tid; j < NMSMAX * 6; j += NTHR) grow[j] = 0.f;
}

// ---------------------------------------------------------------- launch ---
extern "C" void kernel_launch(void* const* d_in, const int* in_sizes, int n_in,
                              void* d_out, int out_size, void* d_ws, size_t ws_size,
                              hipStream_t stream) {
  const float* pred = (const float*)d_in[0];
  float* out = (float*)d_out;
  float* ws = (float*)d_ws;

  const long long boxes_f = (long long)NB * NANCH * 4;           //  2,235,392
  const long long rows_f  = (long long)NB * NCLS * NMSMAX * 6;   //    768,000
  const long long st_f    = (long long)NB * NCLS * NANCH;        // 11,176,960
  const long long sidx_f  = (long long)NB * NCLS * NANCH / 2;    //  5,588,480
  const long long ncand_f = NB * NCLS;                           //      1,280

  float* boxes = ws;
  float* rows  = ws + boxes_f;
  float* st    = ws + boxes_f + rows_f;
  unsigned short* sidx = (unsigned short*)(ws + boxes_f + rows_f + st_f);
  int* ncand = (int*)(ws + boxes_f + rows_f + st_f + sidx_f);

  size_t need_full = (size_t)(boxes_f + rows_f + st_f + sidx_f + ncand_f) * sizeof(float);
  bool full = ws_size >= need_full;

  dim3 dgrid((NANCH + DTILE - 1) / DTILE, NB);

  if (full) {
    decode_kernel<<<dgrid, 256, 0, stream>>>(pred, boxes, st);
    sort_kernel<<<NB * NCLS, NTHR, 0, stream>>>(st, sidx, ncand);
    scan_kernel<<<NB * NCLS, 64, 0, stream>>>(boxes, st, sidx, ncand, rows);
  } else {
    decode_kernel<<<dgrid, 256, 0, stream>>>(pred, boxes, nullptr);
    nms_fused_kernel<<<NB * NCLS, NTHR, 0, stream>>>(boxes, pred, rows);
  }
  topk_kernel<<<NB, 512, 0, stream>>>(rows, out);
}